// Round 8
// baseline (347.884 us; speedup 1.0000x reference)
//
#include <hip/hip_runtime.h>
#include <math.h>

#define NN 10000
#define NE 160000
#define NRBF 50
#define WNUM 2304
#define EPSV 1e-5f

#define A_P1 0.125f
#define A_P2 0.17677669529663687f
#define A_P3 0.125f
#define A_P4 0.17677669529663687f
#define INV_SQRT3 0.5773502691896258f
#define INV_SQRT_M0 0.17677669529663687f
#define INV_SQRT_M1 0.25f

typedef __attribute__((ext_vector_type(8))) short bf16x8;
typedef __attribute__((ext_vector_type(4))) float f32x4;
typedef __attribute__((ext_vector_type(4))) int i32x4;

#define MFMA16(a, b, c) __builtin_amdgcn_mfma_f32_16x16x32_bf16(a, b, c, 0, 0, 0)

__device__ __forceinline__ short f2bf(float x) {
  unsigned u = __float_as_uint(x);
  unsigned r = (u + 0x7fffu + ((u >> 16) & 1u)) >> 16;
  return (short)r;
}

// ---- weight prep: transpose + bf16 + fragment-order packing ----
// Per 16-col tile t: 1024 shorts = [chunk(2)][lane(64)][kk(8)].
__global__ void prep_weights(const float* __restrict__ W1, const float* __restrict__ W2,
                             const float* __restrict__ W3, short* __restrict__ W1P,
                             short* __restrict__ W2P, short* __restrict__ W3P) {
  int s = blockIdx.x * 256 + threadIdx.x;
  if (s < WNUM * 64) {
    int t = s >> 10, r = s & 1023;
    int ch = r >> 9, l = (r >> 3) & 63, kk = r & 7;
    int row = t * 16 + (l & 15);
    int k = ((l >> 4) << 3) + (ch << 5) + kk;
    W3P[s] = f2bf(W3[k * WNUM + row]);
  } else if (s < WNUM * 64 + 4096) {
    int s2 = s - WNUM * 64;
    int t = s2 >> 10, r = s2 & 1023;
    int ch = r >> 9, l = (r >> 3) & 63, kk = r & 7;
    int row = t * 16 + (l & 15);
    int k = ((l >> 4) << 3) + (ch << 5) + kk;
    W1P[s2] = f2bf(k < NRBF ? W1[k * 64 + row] : 0.f);
  } else if (s < WNUM * 64 + 8192) {
    int s2 = s - WNUM * 64 - 4096;
    int t = s2 >> 10, r = s2 & 1023;
    int ch = r >> 9, l = (r >> 3) & 63, kk = r & 7;
    int row = t * 16 + (l & 15);
    int k = ((l >> 4) << 3) + (ch << 5) + kk;
    W2P[s2] = f2bf(W2[k * 64 + row]);
  }
}

__global__ void edge_count(const int* __restrict__ eidx, int* __restrict__ deg) {
  int e = blockIdx.x * 256 + threadIdx.x;
  if (e < NE) atomicAdd(&deg[eidx[NE + e]], 1);
}

__global__ __launch_bounds__(256, 4) void edge_kernel(
    const float* __restrict__ h, const int* __restrict__ eidx,
    const float* __restrict__ esh, const float* __restrict__ ef,
    const short* __restrict__ W1P, const float* __restrict__ b1,
    const short* __restrict__ W2P, const float* __restrict__ b2,
    const short* __restrict__ W3P, const float* __restrict__ b3,
    float* __restrict__ agg) {
  __shared__ short buf0[64 * 72];      // ef -> h1 -> h2 (in place)
  // coef (f32, 24KB): s0c[0..2047]=0.125*s0[u] (serves w1 AND w3, A_P1==A_P3),
  // w2c[2048..5119]=A_P2*y0*s1[u][i], d4c[5120..6143]=A_P4/sqrt3*(s1.y1).
  // Aliased as cross-wave reduce scratch after phase C.
  __shared__ float coef[6144];
  __shared__ float y0s[64], y1s[192];
  __shared__ float b1s[64], b2s[64];
  __shared__ int dsts[64];
  float* scratch = coef;

  const int tid = threadIdx.x;
  const int e0 = blockIdx.x * 64;

  // ---- Phase A: staging ----
  for (int idx = tid; idx < 64 * 64; idx += 256) {
    int e = idx >> 6, k = idx & 63;
    float v = (k < NRBF) ? ef[(long)(e0 + e) * NRBF + k] : 0.f;
    buf0[e * 72 + k] = f2bf(v);
  }
  if (tid < 64) { b1s[tid] = b1[tid]; b2s[tid] = b2[tid]; }
  {
    int e = tid >> 2, q = tid & 3;
    int ge = e0 + e;
    int src = eidx[ge];
    float y0 = esh[ge * 4 + 0];
    float y1x = esh[ge * 4 + 1], y1y = esh[ge * 4 + 2], y1z = esh[ge * 4 + 3];
    const float* hs = h + (long)src * 80;
    for (int u = q; u < 32; u += 4) coef[u * 64 + e] = 0.125f * hs[u];
    for (int u = q; u < 16; u += 4) {
      float sx = hs[32 + u * 3], sy = hs[33 + u * 3], sz = hs[34 + u * 3];
      coef[2048 + (0 * 16 + u) * 64 + e] = A_P2 * y0 * sx;
      coef[2048 + (1 * 16 + u) * 64 + e] = A_P2 * y0 * sy;
      coef[2048 + (2 * 16 + u) * 64 + e] = A_P2 * y0 * sz;
      coef[5120 + u * 64 + e] = A_P4 * INV_SQRT3 * (sx * y1x + sy * y1y + sz * y1z);
    }
    if (q == 0) {
      y0s[e] = y0;
      y1s[e] = y1x; y1s[64 + e] = y1y; y1s[128 + e] = y1z;
      dsts[e] = eidx[NE + ge];
    }
  }
  __syncthreads();

  const int wid = tid >> 6, l = tid & 63;
  const int lr = l & 15, lg = l >> 4;
  const int g16 = lg * 4;
  const int er = wid * 16;

  // ---- MLP layer 1 (in place) ----
  {
    bf16x8 a0 = *(const bf16x8*)&buf0[(er + lr) * 72 + lg * 8];
    bf16x8 a1 = *(const bf16x8*)&buf0[(er + lr) * 72 + 32 + lg * 8];
#pragma unroll
    for (int jt = 0; jt < 4; ++jt) {
      const short* wb = W1P + (jt << 10) + (l << 3);
      bf16x8 b0 = *(const bf16x8*)wb;
      bf16x8 b1f = *(const bf16x8*)(wb + 512);
      float bias = b1s[jt * 16 + lr];
      f32x4 d = {bias, bias, bias, bias};
      d = MFMA16(a0, b0, d);
      d = MFMA16(a1, b1f, d);
#pragma unroll
      for (int r = 0; r < 4; ++r) {
        float x = d[r];
        x = x / (1.f + __expf(-x));
        buf0[(er + lg * 4 + r) * 72 + jt * 16 + lr] = f2bf(x);
      }
    }
  }
  __syncthreads();

  // ---- MLP layer 2 (in place) ----
  {
    bf16x8 a0 = *(const bf16x8*)&buf0[(er + lr) * 72 + lg * 8];
    bf16x8 a1 = *(const bf16x8*)&buf0[(er + lr) * 72 + 32 + lg * 8];
#pragma unroll
    for (int jt = 0; jt < 4; ++jt) {
      const short* wb = W2P + (jt << 10) + (l << 3);
      bf16x8 b0 = *(const bf16x8*)wb;
      bf16x8 b1f = *(const bf16x8*)(wb + 512);
      float bias = b2s[jt * 16 + lr];
      f32x4 d = {bias, bias, bias, bias};
      d = MFMA16(a0, b0, d);
      d = MFMA16(a1, b1f, d);
#pragma unroll
      for (int r = 0; r < 4; ++r) {
        float x = d[r];
        x = x / (1.f + __expf(-x));
        buf0[(er + lg * 4 + r) * 72 + jt * 16 + lr] = f2bf(x);
      }
    }
  }
  __syncthreads();

  // ---- Phase C ----
  bf16x8 a0g[4], a1g[4];
#pragma unroll
  for (int g = 0; g < 4; ++g) {
    a0g[g] = *(const bf16x8*)&buf0[(g * 16 + lr) * 72 + lg * 8];
    a1g[g] = *(const bf16x8*)&buf0[(g * 16 + lr) * 72 + 32 + lg * 8];
  }

// prefetch-ring load of one tile
#define LD(T, RB0, RB1, RBI)                                        \
  {                                                                 \
    RB0 = *(const bf16x8*)(W3P + ((T) << 10) + (l << 3));           \
    RB1 = *(const bf16x8*)(W3P + ((T) << 10) + 512 + (l << 3));     \
    RBI = b3[((T) << 4) + lr];                                      \
  }

  if (wid < 2) {
    // m0 waves: wid0 = w1 u0..23 ; wid1 = w1 u24..31 -> *y0 -> w4 p0..15
    f32x4 accA[4], accB[4];
#pragma unroll
    for (int g = 0; g < 4; ++g) {
      accA[g] = (f32x4){0, 0, 0, 0};
      accB[g] = (f32x4){0, 0, 0, 0};
    }
    const int ub = (wid == 0) ? 0 : 24;
    const int ue = (wid == 0) ? 24 : 32;
    bf16x8 pE0, pE1, pO0, pO1;
    float pbe, pbo;
    LD(2 * ub, pE0, pE1, pbe);
    LD(2 * ub + 1, pO0, pO1, pbo);
#pragma unroll 2
    for (int u = ub; u < ue; ++u) {
      bf16x8 E0 = pE0, E1 = pE1, O0 = pO0, O1 = pO1;
      float be = pbe, bo = pbo;
      if (u + 1 < ue) {
        LD(2 * u + 2, pE0, pE1, pbe);
        LD(2 * u + 3, pO0, pO1, pbo);
      }
#pragma unroll
      for (int g = 0; g < 4; ++g) {
        f32x4 c = *(const f32x4*)&coef[u * 64 + g * 16 + g16];
        f32x4 d = {be, be, be, be};
        d = MFMA16(a0g[g], E0, d);
        f32x4 v = MFMA16(a1g[g], E1, d);
        f32x4 d2 = {bo, bo, bo, bo};
        d2 = MFMA16(a0g[g], O0, d2);
        f32x4 v2 = MFMA16(a1g[g], O1, d2);
#pragma unroll
        for (int r = 0; r < 4; ++r) {
          accA[g][r] += c[r] * v[r];
          accB[g][r] += c[r] * v2[r];
        }
      }
    }
    // apply y0 to the w1 partial
#pragma unroll
    for (int g = 0; g < 4; ++g) {
      f32x4 y0v = *(const f32x4*)&y0s[g * 16 + g16];
#pragma unroll
      for (int r = 0; r < 4; ++r) { accA[g][r] *= y0v[r]; accB[g][r] *= y0v[r]; }
    }
    if (wid == 1) {
      // w4: tiles 112+2p / 113+2p, coef d4c, no y0
      LD(112, pE0, pE1, pbe);
      LD(113, pO0, pO1, pbo);
#pragma unroll 2
      for (int p = 0; p < 16; ++p) {
        bf16x8 E0 = pE0, E1 = pE1, O0 = pO0, O1 = pO1;
        float be = pbe, bo = pbo;
        if (p + 1 < 16) {
          LD(114 + 2 * p, pE0, pE1, pbe);
          LD(115 + 2 * p, pO0, pO1, pbo);
        }
#pragma unroll
        for (int g = 0; g < 4; ++g) {
          f32x4 c = *(const f32x4*)&coef[5120 + p * 64 + g * 16 + g16];
          f32x4 d = {be, be, be, be};
          d = MFMA16(a0g[g], E0, d);
          f32x4 v = MFMA16(a1g[g], E1, d);
          f32x4 d2 = {bo, bo, bo, bo};
          d2 = MFMA16(a0g[g], O0, d2);
          f32x4 v2 = MFMA16(a1g[g], O1, d2);
#pragma unroll
          for (int r = 0; r < 4; ++r) {
            accA[g][r] += c[r] * v[r];
            accB[g][r] += c[r] * v2[r];
          }
        }
      }
    }
    // reduce + scatter m0
    __syncthreads();
    if (wid == 1) {
#pragma unroll
      for (int g = 0; g < 4; ++g) {
        *(f32x4*)&scratch[l * 36 + g * 4] = accA[g];
        *(f32x4*)&scratch[l * 36 + 16 + g * 4] = accB[g];
      }
    }
    __syncthreads();
    if (wid == 0) {
#pragma unroll
      for (int g = 0; g < 4; ++g) {
        f32x4 t0 = *(const f32x4*)&scratch[l * 36 + g * 4];
        f32x4 t1 = *(const f32x4*)&scratch[l * 36 + 16 + g * 4];
        i32x4 dd = *(const i32x4*)&dsts[g * 16 + g16];
#pragma unroll
        for (int r = 0; r < 4; ++r) {
          float* base = agg + (long)dd[r] * 80;
          atomicAdd(base + lr, accA[g][r] + t0[r]);
          atomicAdd(base + 16 + lr, accB[g][r] + t1[r]);
        }
      }
    }
  } else {
    // m1 waves: wid2 = w2 u0..15 (y0 baked) + w3 u0..7 ; wid3 = w3 u8..31
    f32x4 m1a[3][4], t3[4];
#pragma unroll
    for (int g = 0; g < 4; ++g) {
      m1a[0][g] = (f32x4){0, 0, 0, 0};
      m1a[1][g] = (f32x4){0, 0, 0, 0};
      m1a[2][g] = (f32x4){0, 0, 0, 0};
      t3[g] = (f32x4){0, 0, 0, 0};
    }
    bf16x8 pB0, pB1;
    float pb;
    if (wid == 2) {
      LD(64, pB0, pB1, pb);
#pragma unroll 2
      for (int u = 0; u < 16; ++u) {
        bf16x8 B0 = pB0, B1 = pB1;
        float bb = pb;
        if (u + 1 < 16) LD(65 + u, pB0, pB1, pb);
#pragma unroll
        for (int g = 0; g < 4; ++g) {
          f32x4 c0 = *(const f32x4*)&coef[2048 + (0 * 16 + u) * 64 + g * 16 + g16];
          f32x4 c1 = *(const f32x4*)&coef[2048 + (1 * 16 + u) * 64 + g * 16 + g16];
          f32x4 c2 = *(const f32x4*)&coef[2048 + (2 * 16 + u) * 64 + g * 16 + g16];
          f32x4 d = {bb, bb, bb, bb};
          d = MFMA16(a0g[g], B0, d);
          f32x4 v = MFMA16(a1g[g], B1, d);
#pragma unroll
          for (int r = 0; r < 4; ++r) {
            m1a[0][g][r] += c0[r] * v[r];
            m1a[1][g][r] += c1[r] * v[r];
            m1a[2][g][r] += c2[r] * v[r];
          }
        }
      }
    }
    const int wb3 = (wid == 2) ? 0 : 8;
    const int we3 = (wid == 2) ? 8 : 32;
    LD(80 + wb3, pB0, pB1, pb);
#pragma unroll 2
    for (int u = wb3; u < we3; ++u) {
      bf16x8 B0 = pB0, B1 = pB1;
      float bb = pb;
      if (u + 1 < we3) LD(81 + u, pB0, pB1, pb);
#pragma unroll
      for (int g = 0; g < 4; ++g) {
        f32x4 c = *(const f32x4*)&coef[u * 64 + g * 16 + g16];
        f32x4 d = {bb, bb, bb, bb};
        d = MFMA16(a0g[g], B0, d);
        f32x4 v = MFMA16(a1g[g], B1, d);
#pragma unroll
        for (int r = 0; r < 4; ++r) t3[g][r] += c[r] * v[r];
      }
    }
    // fold t3 with y1
#pragma unroll
    for (int g = 0; g < 4; ++g) {
      f32x4 yx = *(const f32x4*)&y1s[g * 16 + g16];
      f32x4 yy = *(const f32x4*)&y1s[64 + g * 16 + g16];
      f32x4 yz = *(const f32x4*)&y1s[128 + g * 16 + g16];
#pragma unroll
      for (int r = 0; r < 4; ++r) {
        m1a[0][g][r] += yx[r] * t3[g][r];
        m1a[1][g][r] += yy[r] * t3[g][r];
        m1a[2][g][r] += yz[r] * t3[g][r];
      }
    }
    // reduce + scatter m1
    __syncthreads();
    if (wid == 3) {
#pragma unroll
      for (int g = 0; g < 4; ++g) {
        *(f32x4*)&scratch[2304 + l * 52 + g * 4] = m1a[0][g];
        *(f32x4*)&scratch[2304 + l * 52 + 16 + g * 4] = m1a[1][g];
        *(f32x4*)&scratch[2304 + l * 52 + 32 + g * 4] = m1a[2][g];
      }
    }
    __syncthreads();
    if (wid == 2) {
#pragma unroll
      for (int g = 0; g < 4; ++g) {
        f32x4 t0 = *(const f32x4*)&scratch[2304 + l * 52 + g * 4];
        f32x4 t1 = *(const f32x4*)&scratch[2304 + l * 52 + 16 + g * 4];
        f32x4 t2 = *(const f32x4*)&scratch[2304 + l * 52 + 32 + g * 4];
        i32x4 dd = *(const i32x4*)&dsts[g * 16 + g16];
#pragma unroll
        for (int r = 0; r < 4; ++r) {
          float* base = agg + (long)dd[r] * 80;
          atomicAdd(base + 32 + lr * 3 + 0, m1a[0][g][r] + t0[r]);
          atomicAdd(base + 32 + lr * 3 + 1, m1a[1][g][r] + t1[r]);
          atomicAdd(base + 32 + lr * 3 + 2, m1a[2][g][r] + t2[r]);
        }
      }
    }
  }
#undef LD
}

// ---- fused gather + self-interaction + stats (wave per node) ----
__global__ __launch_bounds__(256) void node_fused(
    const float* __restrict__ h, const float* __restrict__ A0,
    const float* __restrict__ A1p, const float* __restrict__ agg,
    const int* __restrict__ deg, float* __restrict__ outpre,
    float* __restrict__ stats) {
  __shared__ float A0s[1024], A1ps[256], red[96];
  const int tid = threadIdx.x;
  for (int i = tid; i < 1280; i += 256) {
    if (i < 1024) A0s[i] = A0[i];
    else A1ps[i - 1024] = A1p[i - 1024];
  }
  if (tid < 96) red[tid] = 0.f;
  __syncthreads();
  const int wid = tid >> 6, l = tid & 63;
  const int n = blockIdx.x * 4 + wid;
  if (n < NN) {
    const float inv = 1.f / fmaxf((float)deg[n], 1.f);
    float a0 = agg[(long)n * 80 + l];
    float a1 = (l < 16) ? agg[(long)n * 80 + 64 + l] : 0.f;
    const float* hr = h + (long)n * 80;
    float valA;
    if (l < 32) {
      float x = 0.f;
#pragma unroll 8
      for (int u = 0; u < 32; ++u) x += hr[u] * A0s[u * 32 + l];
      valA = x * INV_SQRT_M0 + a0 * inv;
    } else {
      int j = l - 32, w = j / 3, i3 = j - w * 3;
      float x = 0.f;
#pragma unroll 8
      for (int u = 0; u < 16; ++u) x += hr[32 + u * 3 + i3] * A1ps[u * 16 + w];
      valA = x * INV_SQRT_M1 + a0 * inv;
    }
    float valB = 0.f;
    if (l < 16) {
      int j = 32 + l, w = j / 3, i3 = j - w * 3;
      float x = 0.f;
#pragma unroll 8
      for (int u = 0; u < 16; ++u) x += hr[32 + u * 3 + i3] * A1ps[u * 16 + w];
      valB = x * INV_SQRT_M1 + a1 * inv;
    }
    outpre[(long)n * 80 + l] = valA;
    if (l < 16) outpre[(long)n * 80 + 64 + l] = valB;
    if (l < 32) {
      atomicAdd(&red[l], valA);
      atomicAdd(&red[32 + l], valA * valA);
    } else {
      int w = (l - 32) / 3;
      atomicAdd(&red[64 + w], valA * valA);
    }
    if (l < 16) {
      int w = (32 + l) / 3;
      atomicAdd(&red[64 + w], valB * valB);
    }
  }
  __syncthreads();
  if (tid < 80) atomicAdd(&stats[tid], red[tid]);
}

__global__ void node_b(const float* __restrict__ outpre, const float* __restrict__ stats,
                       const float* __restrict__ bnw0, const float* __restrict__ bnb0,
                       const float* __restrict__ bnw1, const float* __restrict__ h,
                       float* __restrict__ out) {
  int idx = blockIdx.x * 256 + threadIdx.x;
  if (idx >= NN * 80) return;
  int c = idx % 80;
  float v = outpre[idx];
  const float invN = 1.f / NN;
  float o;
  if (c < 32) {
    float mu = stats[c] * invN;
    float var = stats[32 + c] * invN - mu * mu;
    o = (v - mu) * rsqrtf(var + EPSV) * bnw0[c] + bnb0[c];
  } else {
    int u = (c - 32) / 3;
    float nr = stats[64 + u] * invN;
    o = v * rsqrtf(nr + EPSV) * bnw1[u];
  }
  out[idx] = o + h[idx];
}

extern "C" void kernel_launch(void* const* d_in, const int* in_sizes, int n_in,
                              void* d_out, int out_size, void* d_ws, size_t ws_size,
                              hipStream_t stream) {
  const float* h    = (const float*)d_in[0];
  const int*   eidx = (const int*)d_in[1];
  const float* esh  = (const float*)d_in[2];
  const float* ef   = (const float*)d_in[3];
  const float* W1   = (const float*)d_in[4];
  const float* b1   = (const float*)d_in[5];
  const float* W2   = (const float*)d_in[6];
  const float* b2   = (const float*)d_in[7];
  const float* W3   = (const float*)d_in[8];
  const float* b3   = (const float*)d_in[9];
  const float* A0   = (const float*)d_in[10];
  const float* A1p  = (const float*)d_in[11];
  const float* bnw0 = (const float*)d_in[12];
  const float* bnb0 = (const float*)d_in[13];
  const float* bnw1 = (const float*)d_in[14];
  float* out = (float*)d_out;

  float* ws = (float*)d_ws;
  float* agg    = ws;                       // 800000
  float* stats  = ws + 800000;              // 80
  float* outpre = ws + 800080;              // 800000
  short* W3P    = (short*)(ws + 1600080);   // 147456 shorts
  short* W1P    = W3P + WNUM * 64;          // 4096
  short* W2P    = W1P + 4096;               // 4096
  int*   deg    = (int*)(ws + 1677904);     // 10000

  hipMemsetAsync(agg, 0, (size_t)800080 * sizeof(float), stream);
  hipMemsetAsync(deg, 0, (size_t)10000 * sizeof(int), stream);

  prep_weights<<<(WNUM * 64 + 8192 + 255) / 256, 256, 0, stream>>>(W1, W2, W3, W1P,
                                                                   W2P, W3P);
  edge_count<<<(NE + 255) / 256, 256, 0, stream>>>(eidx, deg);
  edge_kernel<<<NE / 64, 256, 0, stream>>>(h, eidx, esh, ef, W1P, b1, W2P, b2, W3P, b3,
                                           agg);
  node_fused<<<(NN + 3) / 4, 256, 0, stream>>>(h, A0, A1p, agg, deg, outpre, stats);
  node_b<<<(NN * 80 + 255) / 256, 256, 0, stream>>>(outpre, stats, bnw0, bnb0, bnw1, h,
                                                    out);
}

// Round 9
// 274.755 us; speedup vs baseline: 1.2662x; 1.2662x over previous
//
#include <hip/hip_runtime.h>
#include <math.h>

#define NN 10000
#define NE 160000
#define NRBF 50
#define WNUM 2304
#define EPSV 1e-5f

#define A_P1 0.125f
#define A_P2 0.17677669529663687f
#define A_P3 0.125f
#define A_P4 0.17677669529663687f
#define INV_SQRT3 0.5773502691896258f
#define INV_SQRT_M0 0.17677669529663687f
#define INV_SQRT_M1 0.25f

typedef __attribute__((ext_vector_type(8))) short bf16x8;
typedef __attribute__((ext_vector_type(4))) float f32x4;
typedef __attribute__((ext_vector_type(4))) int i32x4;

#define MFMA16(a, b, c) __builtin_amdgcn_mfma_f32_16x16x32_bf16(a, b, c, 0, 0, 0)

__device__ __forceinline__ short f2bf(float x) {
  unsigned u = __float_as_uint(x);
  unsigned r = (u + 0x7fffu + ((u >> 16) & 1u)) >> 16;
  return (short)r;
}

// ---- weight prep: transpose + bf16 + fragment-order packing ----
// Per 16-col tile t: 1024 shorts = [chunk(2)][lane(64)][kk(8)].
// Lane l, chunk c holds B[row = t*16 + (l&15)][k = (l>>4)*8 + c*32 + kk].
__global__ void prep_weights(const float* __restrict__ W1, const float* __restrict__ W2,
                             const float* __restrict__ W3, short* __restrict__ W1P,
                             short* __restrict__ W2P, short* __restrict__ W3P) {
  int s = blockIdx.x * 256 + threadIdx.x;
  if (s < WNUM * 64) {
    int t = s >> 10, r = s & 1023;
    int ch = r >> 9, l = (r >> 3) & 63, kk = r & 7;
    int row = t * 16 + (l & 15);
    int k = ((l >> 4) << 3) + (ch << 5) + kk;
    W3P[s] = f2bf(W3[k * WNUM + row]);
  } else if (s < WNUM * 64 + 4096) {
    int s2 = s - WNUM * 64;
    int t = s2 >> 10, r = s2 & 1023;
    int ch = r >> 9, l = (r >> 3) & 63, kk = r & 7;
    int row = t * 16 + (l & 15);
    int k = ((l >> 4) << 3) + (ch << 5) + kk;
    W1P[s2] = f2bf(k < NRBF ? W1[k * 64 + row] : 0.f);
  } else if (s < WNUM * 64 + 8192) {
    int s2 = s - WNUM * 64 - 4096;
    int t = s2 >> 10, r = s2 & 1023;
    int ch = r >> 9, l = (r >> 3) & 63, kk = r & 7;
    int row = t * 16 + (l & 15);
    int k = ((l >> 4) << 3) + (ch << 5) + kk;
    W2P[s2] = f2bf(W2[k * 64 + row]);
  }
}

__global__ __launch_bounds__(256, 3) void edge_kernel(
    const float* __restrict__ h, const int* __restrict__ eidx,
    const float* __restrict__ esh, const float* __restrict__ ef,
    const short* __restrict__ W1P, const float* __restrict__ b1,
    const short* __restrict__ W2P, const float* __restrict__ b2,
    const short* __restrict__ W3P, const float* __restrict__ b3,
    float* __restrict__ agg, float* __restrict__ cnt) {
  __shared__ short act[64 * 72];       // ef -> h1 -> h2 (in-place MLP)
  __shared__ short bstage[2][4096];    // double buffer: 4 tiles/chunk (2 per half)
  // coef (f32, 24 KB): s0c[0..2047]=0.125*s0[u]; w2c x/y/z at 2048/3072/4096 (+u*64);
  // d4c[5120..6143]. Reused as cross-wave reduce scratch after phase C.
  __shared__ float coef[6144];
  __shared__ float y0s[64], y1s[192];
  __shared__ float b1s[64], b2s[64];
  __shared__ int dsts[64];
  float* scratch = coef;

  const int tid = threadIdx.x;
  const int e0 = blockIdx.x * 64;

  // ---- Phase A: staging ----
  for (int idx = tid; idx < 64 * 64; idx += 256) {
    int e = idx >> 6, k = idx & 63;
    float v = (k < NRBF) ? ef[(long)(e0 + e) * NRBF + k] : 0.f;
    act[e * 72 + k] = f2bf(v);
  }
  if (tid < 64) { b1s[tid] = b1[tid]; b2s[tid] = b2[tid]; }
  {
    int e = tid >> 2, q = tid & 3;
    int ge = e0 + e;
    int src = eidx[ge];
    float y0 = esh[ge * 4 + 0];
    float y1x = esh[ge * 4 + 1], y1y = esh[ge * 4 + 2], y1z = esh[ge * 4 + 3];
    const float* hs = h + (long)src * 80;
    for (int u = q; u < 32; u += 4) coef[u * 64 + e] = 0.125f * hs[u];
    for (int u = q; u < 16; u += 4) {
      float sx = hs[32 + u * 3], sy = hs[33 + u * 3], sz = hs[34 + u * 3];
      coef[2048 + u * 64 + e] = A_P2 * sx;
      coef[3072 + u * 64 + e] = A_P2 * sy;
      coef[4096 + u * 64 + e] = A_P2 * sz;
      coef[5120 + u * 64 + e] = A_P4 * INV_SQRT3 * (sx * y1x + sy * y1y + sz * y1z);
    }
    if (q == 0) {
      y0s[e] = y0;
      y1s[e] = y1x; y1s[64 + e] = y1y; y1s[128 + e] = y1z;
      dsts[e] = eidx[NE + ge];
    }
  }
  __syncthreads();

  const int wid = tid >> 6, l = tid & 63;
  const int lr = l & 15, lg = l >> 4;
  const int er = wid * 16;

  // ---- MLP layer 1 (in place) ----
  {
    bf16x8 a0 = *(const bf16x8*)&act[(er + lr) * 72 + lg * 8];
    bf16x8 a1 = *(const bf16x8*)&act[(er + lr) * 72 + 32 + lg * 8];
#pragma unroll
    for (int jt = 0; jt < 4; ++jt) {
      const short* wb = W1P + (jt << 10) + (l << 3);
      bf16x8 b0 = *(const bf16x8*)wb;
      bf16x8 b1f = *(const bf16x8*)(wb + 512);
      float bias = b1s[jt * 16 + lr];
      f32x4 d = {bias, bias, bias, bias};
      d = MFMA16(a0, b0, d);
      d = MFMA16(a1, b1f, d);
#pragma unroll
      for (int r = 0; r < 4; ++r) {
        float x = d[r];
        x = x / (1.f + __expf(-x));
        act[(er + lg * 4 + r) * 72 + jt * 16 + lr] = f2bf(x);
      }
    }
  }
  __syncthreads();

  // ---- MLP layer 2 (in place) ----
  {
    bf16x8 a0 = *(const bf16x8*)&act[(er + lr) * 72 + lg * 8];
    bf16x8 a1 = *(const bf16x8*)&act[(er + lr) * 72 + 32 + lg * 8];
#pragma unroll
    for (int jt = 0; jt < 4; ++jt) {
      const short* wb = W2P + (jt << 10) + (l << 3);
      bf16x8 b0 = *(const bf16x8*)wb;
      bf16x8 b1f = *(const bf16x8*)(wb + 512);
      float bias = b2s[jt * 16 + lr];
      f32x4 d = {bias, bias, bias, bias};
      d = MFMA16(a0, b0, d);
      d = MFMA16(a1, b1f, d);
#pragma unroll
      for (int r = 0; r < 4; ++r) {
        float x = d[r];
        x = x / (1.f + __expf(-x));
        act[(er + lg * 4 + r) * 72 + jt * 16 + lr] = f2bf(x);
      }
    }
  }
  __syncthreads();

  // ---- Phase C: wave = (edge-pair gpair, tile-half); B streamed via LDS dbuf ----
  const int gpair = wid & 1, half = wid >> 1;
  const int rowA = gpair * 32, rowB = gpair * 32 + 16;
  const int r4A = rowA + lg * 4, r4B = rowB + lg * 4;

  bf16x8 aA0 = *(const bf16x8*)&act[(rowA + lr) * 72 + lg * 8];
  bf16x8 aA1 = *(const bf16x8*)&act[(rowA + lr) * 72 + 32 + lg * 8];
  bf16x8 aB0 = *(const bf16x8*)&act[(rowB + lr) * 72 + lg * 8];
  bf16x8 aB1 = *(const bf16x8*)&act[(rowB + lr) * 72 + 32 + lg * 8];

  f32x4 s0A = {0,0,0,0}, s1A = {0,0,0,0}, s0B = {0,0,0,0}, s1B = {0,0,0,0};
  f32x4 mxA = {0,0,0,0}, myA = {0,0,0,0}, mzA = {0,0,0,0};
  f32x4 mxB = {0,0,0,0}, myB = {0,0,0,0}, mzB = {0,0,0,0};
  f32x4 t3A = {0,0,0,0}, t3B = {0,0,0,0};

  const char* W3Pb = (const char*)W3P;
  // prologue: stage chunk 0 (half0 tiles 0,1 ; half1 tiles 72,73)
  {
    i32x4 r0 = *(const i32x4*)(W3Pb + (size_t)0 * 2048 + tid * 16);
    i32x4 r1 = *(const i32x4*)(W3Pb + (size_t)72 * 2048 + tid * 16);
    char* d = (char*)&bstage[0][0];
    *(i32x4*)(d + tid * 16) = r0;
    *(i32x4*)(d + 4096 + tid * 16) = r1;
  }
  float cb0 = b3[(72 * half) * 16 + lr];
  float cb1 = b3[(72 * half + 1) * 16 + lr];
  __syncthreads();

#pragma unroll 2
  for (int c = 0; c < 36; ++c) {
    i32x4 n0, n1;
    float q0 = 0.f, q1 = 0.f;
    const bool more = (c + 1 < 36);
    if (more) {  // issue next chunk's loads early (latency hides under compute)
      n0 = *(const i32x4*)(W3Pb + (size_t)(2 * c + 2) * 2048 + tid * 16);
      n1 = *(const i32x4*)(W3Pb + (size_t)(74 + 2 * c) * 2048 + tid * 16);
      q0 = b3[(72 * half + 2 * c + 2) * 16 + lr];
      q1 = b3[(72 * half + 2 * c + 3) * 16 + lr];
    }
    // compute chunk c from LDS
    const short* bb = &bstage[c & 1][half * 2048];
    bf16x8 E0 = *(const bf16x8*)(bb + (l << 3));
    bf16x8 E1 = *(const bf16x8*)(bb + 512 + (l << 3));
    bf16x8 O0 = *(const bf16x8*)(bb + 1024 + (l << 3));
    bf16x8 O1 = *(const bf16x8*)(bb + 1536 + (l << 3));
    f32x4 dEA = {cb0, cb0, cb0, cb0}, dEB = dEA;
    dEA = MFMA16(aA0, E0, dEA);
    f32x4 vEA = MFMA16(aA1, E1, dEA);
    dEB = MFMA16(aB0, E0, dEB);
    f32x4 vEB = MFMA16(aB1, E1, dEB);
    f32x4 dOA = {cb1, cb1, cb1, cb1}, dOB = dOA;
    dOA = MFMA16(aA0, O0, dOA);
    f32x4 vOA = MFMA16(aA1, O1, dOA);
    dOB = MFMA16(aB0, O0, dOB);
    f32x4 vOB = MFMA16(aB1, O1, dOB);

    if (half == 0) {
      if (c < 32) {  // w1: u=c, shared coef, even->s0, odd->s1
        f32x4 cA = *(const f32x4*)&coef[c * 64 + r4A];
        f32x4 cB = *(const f32x4*)&coef[c * 64 + r4B];
#pragma unroll
        for (int r = 0; r < 4; ++r) {
          s0A[r] += cA[r] * vEA[r]; s1A[r] += cA[r] * vOA[r];
          s0B[r] += cB[r] * vEB[r]; s1B[r] += cB[r] * vOB[r];
        }
      } else {  // w2: u0=2(c-32) on even tile, u1=u0+1 on odd
        int u0 = 2 * (c - 32), u1 = u0 + 1;
        f32x4 cx0A = *(const f32x4*)&coef[2048 + u0 * 64 + r4A];
        f32x4 cy0A = *(const f32x4*)&coef[3072 + u0 * 64 + r4A];
        f32x4 cz0A = *(const f32x4*)&coef[4096 + u0 * 64 + r4A];
        f32x4 cx1A = *(const f32x4*)&coef[2048 + u1 * 64 + r4A];
        f32x4 cy1A = *(const f32x4*)&coef[3072 + u1 * 64 + r4A];
        f32x4 cz1A = *(const f32x4*)&coef[4096 + u1 * 64 + r4A];
        f32x4 cx0B = *(const f32x4*)&coef[2048 + u0 * 64 + r4B];
        f32x4 cy0B = *(const f32x4*)&coef[3072 + u0 * 64 + r4B];
        f32x4 cz0B = *(const f32x4*)&coef[4096 + u0 * 64 + r4B];
        f32x4 cx1B = *(const f32x4*)&coef[2048 + u1 * 64 + r4B];
        f32x4 cy1B = *(const f32x4*)&coef[3072 + u1 * 64 + r4B];
        f32x4 cz1B = *(const f32x4*)&coef[4096 + u1 * 64 + r4B];
#pragma unroll
        for (int r = 0; r < 4; ++r) {
          mxA[r] += cx0A[r] * vEA[r] + cx1A[r] * vOA[r];
          myA[r] += cy0A[r] * vEA[r] + cy1A[r] * vOA[r];
          mzA[r] += cz0A[r] * vEA[r] + cz1A[r] * vOA[r];
          mxB[r] += cx0B[r] * vEB[r] + cx1B[r] * vOB[r];
          myB[r] += cy0B[r] * vEB[r] + cy1B[r] * vOB[r];
          mzB[r] += cz0B[r] * vEB[r] + cz1B[r] * vOB[r];
        }
      }
    } else {
      if (c < 4) {  // w2: u0=8+2c, u1=u0+1
        int u0 = 8 + 2 * c, u1 = u0 + 1;
        f32x4 cx0A = *(const f32x4*)&coef[2048 + u0 * 64 + r4A];
        f32x4 cy0A = *(const f32x4*)&coef[3072 + u0 * 64 + r4A];
        f32x4 cz0A = *(const f32x4*)&coef[4096 + u0 * 64 + r4A];
        f32x4 cx1A = *(const f32x4*)&coef[2048 + u1 * 64 + r4A];
        f32x4 cy1A = *(const f32x4*)&coef[3072 + u1 * 64 + r4A];
        f32x4 cz1A = *(const f32x4*)&coef[4096 + u1 * 64 + r4A];
        f32x4 cx0B = *(const f32x4*)&coef[2048 + u0 * 64 + r4B];
        f32x4 cy0B = *(const f32x4*)&coef[3072 + u0 * 64 + r4B];
        f32x4 cz0B = *(const f32x4*)&coef[4096 + u0 * 64 + r4B];
        f32x4 cx1B = *(const f32x4*)&coef[2048 + u1 * 64 + r4B];
        f32x4 cy1B = *(const f32x4*)&coef[3072 + u1 * 64 + r4B];
        f32x4 cz1B = *(const f32x4*)&coef[4096 + u1 * 64 + r4B];
#pragma unroll
        for (int r = 0; r < 4; ++r) {
          mxA[r] += cx0A[r] * vEA[r] + cx1A[r] * vOA[r];
          myA[r] += cy0A[r] * vEA[r] + cy1A[r] * vOA[r];
          mzA[r] += cz0A[r] * vEA[r] + cz1A[r] * vOA[r];
          mxB[r] += cx0B[r] * vEB[r] + cx1B[r] * vOB[r];
          myB[r] += cy0B[r] * vEB[r] + cy1B[r] * vOB[r];
          mzB[r] += cz0B[r] * vEB[r] + cz1B[r] * vOB[r];
        }
      } else if (c < 20) {  // w3: u0=2(c-4), u1=u0+1 -> t3
        int u0 = 2 * (c - 4), u1 = u0 + 1;
        f32x4 cA0 = *(const f32x4*)&coef[u0 * 64 + r4A];
        f32x4 cA1 = *(const f32x4*)&coef[u1 * 64 + r4A];
        f32x4 cB0 = *(const f32x4*)&coef[u0 * 64 + r4B];
        f32x4 cB1 = *(const f32x4*)&coef[u1 * 64 + r4B];
#pragma unroll
        for (int r = 0; r < 4; ++r) {
          t3A[r] += cA0[r] * vEA[r] + cA1[r] * vOA[r];
          t3B[r] += cB0[r] * vEB[r] + cB1[r] * vOB[r];
        }
      } else {  // w4: p=c-20, shared coef, even->s0, odd->s1
        f32x4 cA = *(const f32x4*)&coef[5120 + (c - 20) * 64 + r4A];
        f32x4 cB = *(const f32x4*)&coef[5120 + (c - 20) * 64 + r4B];
#pragma unroll
        for (int r = 0; r < 4; ++r) {
          s0A[r] += cA[r] * vEA[r]; s1A[r] += cA[r] * vOA[r];
          s0B[r] += cB[r] * vEB[r]; s1B[r] += cB[r] * vOB[r];
        }
      }
    }
    if (more) {  // write staged regs to the other buffer, then publish
      char* d = (char*)&bstage[(c + 1) & 1][0];
      *(i32x4*)(d + tid * 16) = n0;
      *(i32x4*)(d + 4096 + tid * 16) = n1;
      cb0 = q0; cb1 = q1;
    }
    __syncthreads();
  }

  // ---- finalize scales ----
  f32x4 y0A = *(const f32x4*)&y0s[r4A];
  f32x4 y0B = *(const f32x4*)&y0s[r4B];
  if (half == 0) {
#pragma unroll
    for (int r = 0; r < 4; ++r) {
      s0A[r] *= y0A[r]; s1A[r] *= y0A[r]; s0B[r] *= y0B[r]; s1B[r] *= y0B[r];
      mxA[r] *= y0A[r]; myA[r] *= y0A[r]; mzA[r] *= y0A[r];
      mxB[r] *= y0B[r]; myB[r] *= y0B[r]; mzB[r] *= y0B[r];
    }
  } else {
    f32x4 yxA = *(const f32x4*)&y1s[r4A], yxB = *(const f32x4*)&y1s[r4B];
    f32x4 yyA = *(const f32x4*)&y1s[64 + r4A], yyB = *(const f32x4*)&y1s[64 + r4B];
    f32x4 yzA = *(const f32x4*)&y1s[128 + r4A], yzB = *(const f32x4*)&y1s[128 + r4B];
#pragma unroll
    for (int r = 0; r < 4; ++r) {
      mxA[r] = mxA[r] * y0A[r] + yxA[r] * t3A[r];
      myA[r] = myA[r] * y0A[r] + yyA[r] * t3A[r];
      mzA[r] = mzA[r] * y0A[r] + yzA[r] * t3A[r];
      mxB[r] = mxB[r] * y0B[r] + yxB[r] * t3B[r];
      myB[r] = myB[r] * y0B[r] + yyB[r] * t3B[r];
      mzB[r] = mzB[r] * y0B[r] + yzB[r] * t3B[r];
    }
  }

  // ---- cross-half reduce (half1 -> half0 per gpair) over dead coef LDS ----
  if (half == 1) {
    float* p = scratch + gpair * 3072 + l * 44;
    *(f32x4*)(p + 0) = s0A;  *(f32x4*)(p + 4) = s1A;
    *(f32x4*)(p + 8) = mxA;  *(f32x4*)(p + 12) = myA;  *(f32x4*)(p + 16) = mzA;
    *(f32x4*)(p + 20) = s0B; *(f32x4*)(p + 24) = s1B;
    *(f32x4*)(p + 28) = mxB; *(f32x4*)(p + 32) = myB;  *(f32x4*)(p + 36) = mzB;
  }
  __syncthreads();
  if (half == 0) {
    const float* p = scratch + gpair * 3072 + l * 44;
    f32x4 u0 = *(const f32x4*)(p + 0), u1 = *(const f32x4*)(p + 4);
    f32x4 u2 = *(const f32x4*)(p + 8), u3 = *(const f32x4*)(p + 12);
    f32x4 u4 = *(const f32x4*)(p + 16), u5 = *(const f32x4*)(p + 20);
    f32x4 u6 = *(const f32x4*)(p + 24), u7 = *(const f32x4*)(p + 28);
    f32x4 u8 = *(const f32x4*)(p + 32), u9 = *(const f32x4*)(p + 36);
#pragma unroll
    for (int r = 0; r < 4; ++r) {
      s0A[r] += u0[r]; s1A[r] += u1[r]; mxA[r] += u2[r]; myA[r] += u3[r];
      mzA[r] += u4[r]; s0B[r] += u5[r]; s1B[r] += u6[r]; mxB[r] += u7[r];
      myB[r] += u8[r]; mzB[r] += u9[r];
    }
    i32x4 ddA = *(const i32x4*)&dsts[r4A];
    i32x4 ddB = *(const i32x4*)&dsts[r4B];
#pragma unroll
    for (int r = 0; r < 4; ++r) {
      float* base = agg + (long)ddA[r] * 80;
      atomicAdd(base + lr, s0A[r]);
      atomicAdd(base + 16 + lr, s1A[r]);
      atomicAdd(base + 32 + lr * 3 + 0, mxA[r]);
      atomicAdd(base + 32 + lr * 3 + 1, myA[r]);
      atomicAdd(base + 32 + lr * 3 + 2, mzA[r]);
    }
#pragma unroll
    for (int r = 0; r < 4; ++r) {
      float* base = agg + (long)ddB[r] * 80;
      atomicAdd(base + lr, s0B[r]);
      atomicAdd(base + 16 + lr, s1B[r]);
      atomicAdd(base + 32 + lr * 3 + 0, mxB[r]);
      atomicAdd(base + 32 + lr * 3 + 1, myB[r]);
      atomicAdd(base + 32 + lr * 3 + 2, mzB[r]);
    }
  }
  if (tid < 64) atomicAdd(cnt + dsts[tid], 1.0f);
}

__global__ __launch_bounds__(256) void node_a(
    const float* __restrict__ h, const float* __restrict__ A0,
    const float* __restrict__ A1p, const float* __restrict__ agg,
    const float* __restrict__ cnt, float* __restrict__ outpre,
    float* __restrict__ stats) {
  __shared__ float redw[4][80];
  const int tid = threadIdx.x;
  const int wid = tid >> 6, l = tid & 63;
  const int n = blockIdx.x * 256 + tid;
  float x0[32], x1[48];
#pragma unroll
  for (int w = 0; w < 32; w++) x0[w] = 0.f;
#pragma unroll
  for (int c = 0; c < 48; c++) x1[c] = 0.f;
  if (n < NN) {
    const float* hr = h + (long)n * 80;
    const float* ar = agg + (long)n * 80;
    float inv = 1.f / fmaxf(cnt[n], 1.f);
#pragma unroll 1
    for (int u = 0; u < 32; u++) {
      float hu = hr[u];
#pragma unroll
      for (int w = 0; w < 32; w++) x0[w] += hu * A0[u * 32 + w];
    }
#pragma unroll
    for (int w = 0; w < 32; w++) x0[w] = x0[w] * INV_SQRT_M0 + ar[w] * inv;
#pragma unroll 1
    for (int u = 0; u < 16; u++) {
      float a = hr[32 + u * 3], b_ = hr[33 + u * 3], c_ = hr[34 + u * 3];
#pragma unroll
      for (int w = 0; w < 16; w++) {
        float Aw = A1p[u * 16 + w];
        x1[w * 3 + 0] += a * Aw;
        x1[w * 3 + 1] += b_ * Aw;
        x1[w * 3 + 2] += c_ * Aw;
      }
    }
#pragma unroll
    for (int c = 0; c < 48; c++) x1[c] = x1[c] * INV_SQRT_M1 + ar[32 + c] * inv;
    float* opr = outpre + (long)n * 80;
#pragma unroll
    for (int w = 0; w < 32; w++) opr[w] = x0[w];
#pragma unroll
    for (int c = 0; c < 48; c++) opr[32 + c] = x1[c];
  }
#pragma unroll 1
  for (int c = 0; c < 32; ++c) {
    float s = x0[c];
#pragma unroll
    for (int m = 32; m >= 1; m >>= 1) s += __shfl_xor(s, m, 64);
    if (l == 0) redw[wid][c] = s;
  }
#pragma unroll 1
  for (int c = 0; c < 32; ++c) {
    float v = x0[c];
    float s = v * v;
#pragma unroll
    for (int m = 32; m >= 1; m >>= 1) s += __shfl_xor(s, m, 64);
    if (l == 0) redw[wid][32 + c] = s;
  }
#pragma unroll 1
  for (int u = 0; u < 16; ++u) {
    float s = x1[u * 3] * x1[u * 3] + x1[u * 3 + 1] * x1[u * 3 + 1] +
              x1[u * 3 + 2] * x1[u * 3 + 2];
#pragma unroll
    for (int m = 32; m >= 1; m >>= 1) s += __shfl_xor(s, m, 64);
    if (l == 0) redw[wid][64 + u] = s;
  }
  __syncthreads();
  if (tid < 80)
    atomicAdd(&stats[tid],
              redw[0][tid] + redw[1][tid] + redw[2][tid] + redw[3][tid]);
}

__global__ void node_b(const float* __restrict__ outpre, const float* __restrict__ stats,
                       const float* __restrict__ bnw0, const float* __restrict__ bnb0,
                       const float* __restrict__ bnw1, const float* __restrict__ h,
                       float* __restrict__ out) {
  int idx = blockIdx.x * 256 + threadIdx.x;
  if (idx >= NN * 80) return;
  int c = idx % 80;
  float v = outpre[idx];
  const float invN = 1.f / NN;
  float o;
  if (c < 32) {
    float mu = stats[c] * invN;
    float var = stats[32 + c] * invN - mu * mu;
    o = (v - mu) * rsqrtf(var + EPSV) * bnw0[c] + bnb0[c];
  } else {
    int u = (c - 32) / 3;
    float nr = stats[64 + u] * invN;
    o = v * rsqrtf(nr + EPSV) * bnw1[u];
  }
  out[idx] = o + h[idx];
}

extern "C" void kernel_launch(void* const* d_in, const int* in_sizes, int n_in,
                              void* d_out, int out_size, void* d_ws, size_t ws_size,
                              hipStream_t stream) {
  const float* h    = (const float*)d_in[0];
  const int*   eidx = (const int*)d_in[1];
  const float* esh  = (const float*)d_in[2];
  const float* ef   = (const float*)d_in[3];
  const float* W1   = (const float*)d_in[4];
  const float* b1   = (const float*)d_in[5];
  const float* W2   = (const float*)d_in[6];
  const float* b2   = (const float*)d_in[7];
  const float* W3   = (const float*)d_in[8];
  const float* b3   = (const float*)d_in[9];
  const float* A0   = (const float*)d_in[10];
  const float* A1p  = (const float*)d_in[11];
  const float* bnw0 = (const float*)d_in[12];
  const float* bnb0 = (const float*)d_in[13];
  const float* bnw1 = (const float*)d_in[14];
  float* out = (float*)d_out;

  float* ws = (float*)d_ws;
  float* agg    = ws;             // 800000
  float* cnt    = ws + 800000;    // 10000
  float* stats  = ws + 810000;    // 80
  float* outpre = ws + 810080;    // 800000
  short* W3P    = (short*)(ws + 1610080);  // 147456 shorts
  short* W1P    = W3P + WNUM * 64;         // 4096 shorts
  short* W2P    = W1P + 4096;              // 4096 shorts

  hipMemsetAsync(agg, 0, (size_t)810080 * sizeof(float), stream);

  prep_weights<<<(WNUM * 64 + 8192 + 255) / 256, 256, 0, stream>>>(W1, W2, W3, W1P,
                                                                   W2P, W3P);
  edge_kernel<<<NE / 64, 256, 0, stream>>>(h, eidx, esh, ef, W1P, b1, W2P, b2, W3P, b3,
                                           agg, cnt);
  node_a<<<(NN + 255) / 256, 256, 0, stream>>>(h, A0, A1p, agg, cnt, outpre, stats);
  node_b<<<(NN * 80 + 255) / 256, 256, 0, stream>>>(outpre, stats, bnw0, bnb0, bnw1, h,
                                                    out);
}

// Round 10
// 226.584 us; speedup vs baseline: 1.5353x; 1.2126x over previous
//
#include <hip/hip_runtime.h>
#include <math.h>

#define NN 10000
#define NE 160000
#define NRBF 50
#define WNUM 2304
#define EPSV 1e-5f

#define A_P1 0.125f
#define A_P2 0.17677669529663687f
#define A_P3 0.125f
#define A_P4 0.17677669529663687f
#define INV_SQRT3 0.5773502691896258f
#define INV_SQRT_M0 0.17677669529663687f
#define INV_SQRT_M1 0.25f

typedef __attribute__((ext_vector_type(8))) short bf16x8;
typedef __attribute__((ext_vector_type(4))) float f32x4;
typedef __attribute__((ext_vector_type(4))) int i32x4;

#define MFMA16(a, b, c) __builtin_amdgcn_mfma_f32_16x16x32_bf16(a, b, c, 0, 0, 0)

__device__ __forceinline__ short f2bf(float x) {
  unsigned u = __float_as_uint(x);
  unsigned r = (u + 0x7fffu + ((u >> 16) & 1u)) >> 16;
  return (short)r;
}

// ---- weight prep: transpose + bf16 + fragment-order packing ----
// Per 16-col tile t: 1024 shorts = [chunk(2)][lane(64)][kk(8)].
__global__ void prep_weights(const float* __restrict__ W1, const float* __restrict__ W2,
                             const float* __restrict__ W3, short* __restrict__ W1P,
                             short* __restrict__ W2P, short* __restrict__ W3P) {
  int s = blockIdx.x * 256 + threadIdx.x;
  if (s < WNUM * 64) {
    int t = s >> 10, r = s & 1023;
    int ch = r >> 9, l = (r >> 3) & 63, kk = r & 7;
    int row = t * 16 + (l & 15);
    int k = ((l >> 4) << 3) + (ch << 5) + kk;
    W3P[s] = f2bf(W3[k * WNUM + row]);
  } else if (s < WNUM * 64 + 4096) {
    int s2 = s - WNUM * 64;
    int t = s2 >> 10, r = s2 & 1023;
    int ch = r >> 9, l = (r >> 3) & 63, kk = r & 7;
    int row = t * 16 + (l & 15);
    int k = ((l >> 4) << 3) + (ch << 5) + kk;
    W1P[s2] = f2bf(k < NRBF ? W1[k * 64 + row] : 0.f);
  } else if (s < WNUM * 64 + 8192) {
    int s2 = s - WNUM * 64 - 4096;
    int t = s2 >> 10, r = s2 & 1023;
    int ch = r >> 9, l = (r >> 3) & 63, kk = r & 7;
    int row = t * 16 + (l & 15);
    int k = ((l >> 4) << 3) + (ch << 5) + kk;
    W2P[s2] = f2bf(W2[k * 64 + row]);
  }
}

__global__ __launch_bounds__(256, 4) void edge_kernel(
    const float* __restrict__ h, const int* __restrict__ eidx,
    const float* __restrict__ esh, const float* __restrict__ ef,
    const short* __restrict__ W1P, const float* __restrict__ b1,
    const short* __restrict__ W2P, const float* __restrict__ b2,
    const short* __restrict__ W3P, const float* __restrict__ b3,
    float* __restrict__ agg, float* __restrict__ cnt) {
  __shared__ short act[64 * 72];   // ef -> h1 -> h2, in-place MLP (9216 B)
  // coef (24 KB f32): s0c[0..2047]=0.125*s0[u] (serves w1 AND w3);
  // w2c x/y/z at 2048/3072/4096 (+u*64) = A_P2*s1[u][i] (y0 at finalize);
  // d4c[5120..6143]=A_P4/sqrt3*(s1.y1). Reused as reduce scratch after phase C.
  __shared__ float coef[6144];
  __shared__ float y0s[64], y1s[192];
  __shared__ float b1s[64], b2s[64];
  __shared__ int dsts[64];
  float* scratch = coef;

  const int tid = threadIdx.x;
  const int e0 = blockIdx.x * 64;

  // ---- Phase A: staging ----
  for (int idx = tid; idx < 64 * 64; idx += 256) {
    int e = idx >> 6, k = idx & 63;
    float v = (k < NRBF) ? ef[(long)(e0 + e) * NRBF + k] : 0.f;
    act[e * 72 + k] = f2bf(v);
  }
  if (tid < 64) { b1s[tid] = b1[tid]; b2s[tid] = b2[tid]; }
  {
    int e = tid >> 2, q = tid & 3;
    int ge = e0 + e;
    int src = eidx[ge];
    float y0 = esh[ge * 4 + 0];
    float y1x = esh[ge * 4 + 1], y1y = esh[ge * 4 + 2], y1z = esh[ge * 4 + 3];
    const float* hs = h + (long)src * 80;
    for (int u = q; u < 32; u += 4) coef[u * 64 + e] = 0.125f * hs[u];
    for (int u = q; u < 16; u += 4) {
      float sx = hs[32 + u * 3], sy = hs[33 + u * 3], sz = hs[34 + u * 3];
      coef[2048 + u * 64 + e] = A_P2 * sx;
      coef[3072 + u * 64 + e] = A_P2 * sy;
      coef[4096 + u * 64 + e] = A_P2 * sz;
      coef[5120 + u * 64 + e] = A_P4 * INV_SQRT3 * (sx * y1x + sy * y1y + sz * y1z);
    }
    if (q == 0) {
      y0s[e] = y0;
      y1s[e] = y1x; y1s[64 + e] = y1y; y1s[128 + e] = y1z;
      dsts[e] = eidx[NE + ge];
    }
  }
  __syncthreads();

  const int wid = tid >> 6, l = tid & 63;
  const int lr = l & 15, lg = l >> 4;
  const int g16 = lg * 4;
  const int er = wid * 16;

  // ---- MLP layer 1 (in place; rows wave-private, no barrier after) ----
  {
    bf16x8 a0 = *(const bf16x8*)&act[(er + lr) * 72 + lg * 8];
    bf16x8 a1 = *(const bf16x8*)&act[(er + lr) * 72 + 32 + lg * 8];
#pragma unroll
    for (int jt = 0; jt < 4; ++jt) {
      const short* wb = W1P + (jt << 10) + (l << 3);
      bf16x8 b0 = *(const bf16x8*)wb;
      bf16x8 b1f = *(const bf16x8*)(wb + 512);
      float bias = b1s[jt * 16 + lr];
      f32x4 d = {bias, bias, bias, bias};
      d = MFMA16(a0, b0, d);
      d = MFMA16(a1, b1f, d);
#pragma unroll
      for (int r = 0; r < 4; ++r) {
        float x = d[r];
        x = x / (1.f + __expf(-x));
        act[(er + lg * 4 + r) * 72 + jt * 16 + lr] = f2bf(x);
      }
    }
  }
  // ---- MLP layer 2 (in place) ----
  {
    bf16x8 a0 = *(const bf16x8*)&act[(er + lr) * 72 + lg * 8];
    bf16x8 a1 = *(const bf16x8*)&act[(er + lr) * 72 + 32 + lg * 8];
#pragma unroll
    for (int jt = 0; jt < 4; ++jt) {
      const short* wb = W2P + (jt << 10) + (l << 3);
      bf16x8 b0 = *(const bf16x8*)wb;
      bf16x8 b1f = *(const bf16x8*)(wb + 512);
      float bias = b2s[jt * 16 + lr];
      f32x4 d = {bias, bias, bias, bias};
      d = MFMA16(a0, b0, d);
      d = MFMA16(a1, b1f, d);
#pragma unroll
      for (int r = 0; r < 4; ++r) {
        float x = d[r];
        x = x / (1.f + __expf(-x));
        act[(er + lg * 4 + r) * 72 + jt * 16 + lr] = f2bf(x);
      }
    }
  }
  __syncthreads();

  // ---- Phase C: region-split waves; each wave = all 4 edge-groups ----
  bf16x8 a0g[4], a1g[4];
#pragma unroll
  for (int g = 0; g < 4; ++g) {
    a0g[g] = *(const bf16x8*)&act[(g * 16 + lr) * 72 + lg * 8];
    a1g[g] = *(const bf16x8*)&act[(g * 16 + lr) * 72 + 32 + lg * 8];
  }

// tile-pair fold for m0-style regions: even tile -> acc0, odd -> acc1
#define M0_PAIR(TE, COFF)                                            \
  {                                                                  \
    const short* wbE = W3P + ((TE) << 10) + (l << 3);                \
    const short* wbO = W3P + (((TE) + 1) << 10) + (l << 3);          \
    bf16x8 E0 = *(const bf16x8*)wbE;                                 \
    bf16x8 E1 = *(const bf16x8*)(wbE + 512);                         \
    bf16x8 O0 = *(const bf16x8*)wbO;                                 \
    bf16x8 O1 = *(const bf16x8*)(wbO + 512);                         \
    float be = b3[((TE) << 4) + lr];                                 \
    float bo = b3[(((TE) + 1) << 4) + lr];                           \
    _Pragma("unroll")                                                \
    for (int g = 0; g < 4; ++g) {                                    \
      f32x4 c = *(const f32x4*)&coef[(COFF) + g * 16 + g16];         \
      f32x4 d = {be, be, be, be};                                    \
      d = MFMA16(a0g[g], E0, d);                                     \
      f32x4 v = MFMA16(a1g[g], E1, d);                               \
      f32x4 d2 = {bo, bo, bo, bo};                                   \
      d2 = MFMA16(a0g[g], O0, d2);                                   \
      f32x4 v2 = MFMA16(a1g[g], O1, d2);                             \
      _Pragma("unroll")                                              \
      for (int r = 0; r < 4; ++r) {                                  \
        acc0[g][r] += c[r] * v[r];                                   \
        acc1[g][r] += c[r] * v2[r];                                  \
      }                                                              \
    }                                                                \
  }

#define W2_TILE(U)                                                   \
  {                                                                  \
    const short* wb = W3P + ((64 + (U)) << 10) + (l << 3);           \
    bf16x8 B0 = *(const bf16x8*)wb;                                  \
    bf16x8 B1 = *(const bf16x8*)(wb + 512);                          \
    float bb = b3[((64 + (U)) << 4) + lr];                           \
    _Pragma("unroll")                                                \
    for (int g = 0; g < 4; ++g) {                                    \
      f32x4 d = {bb, bb, bb, bb};                                    \
      d = MFMA16(a0g[g], B0, d);                                     \
      f32x4 v = MFMA16(a1g[g], B1, d);                               \
      f32x4 cx = *(const f32x4*)&coef[2048 + (U) * 64 + g * 16 + g16]; \
      f32x4 cy = *(const f32x4*)&coef[3072 + (U) * 64 + g * 16 + g16]; \
      f32x4 cz = *(const f32x4*)&coef[4096 + (U) * 64 + g * 16 + g16]; \
      _Pragma("unroll")                                              \
      for (int r = 0; r < 4; ++r) {                                  \
        mx[g][r] += cx[r] * v[r];                                    \
        my[g][r] += cy[r] * v[r];                                    \
        mz[g][r] += cz[r] * v[r];                                    \
      }                                                              \
    }                                                                \
  }

#define W3_TILE(U)                                                   \
  {                                                                  \
    const short* wb = W3P + ((80 + (U)) << 10) + (l << 3);           \
    bf16x8 B0 = *(const bf16x8*)wb;                                  \
    bf16x8 B1 = *(const bf16x8*)(wb + 512);                          \
    float bb = b3[((80 + (U)) << 4) + lr];                           \
    _Pragma("unroll")                                                \
    for (int g = 0; g < 4; ++g) {                                    \
      f32x4 d = {bb, bb, bb, bb};                                    \
      d = MFMA16(a0g[g], B0, d);                                     \
      f32x4 v = MFMA16(a1g[g], B1, d);                               \
      f32x4 c = *(const f32x4*)&coef[(U) * 64 + g * 16 + g16];       \
      _Pragma("unroll")                                              \
      for (int r = 0; r < 4; ++r) t3[g][r] += c[r] * v[r];           \
    }                                                                \
  }

  if (wid < 2) {
    // ---- m0 waves ----
    f32x4 acc0[4], acc1[4];
#pragma unroll
    for (int g = 0; g < 4; ++g) {
      acc0[g] = (f32x4){0, 0, 0, 0};
      acc1[g] = (f32x4){0, 0, 0, 0};
    }
    if (wid == 0) {
#pragma unroll 2
      for (int u = 0; u < 24; ++u) M0_PAIR(2 * u, u * 64);
#pragma unroll
      for (int g = 0; g < 4; ++g) {
        f32x4 y0v = *(const f32x4*)&y0s[g * 16 + g16];
#pragma unroll
        for (int r = 0; r < 4; ++r) { acc0[g][r] *= y0v[r]; acc1[g][r] *= y0v[r]; }
      }
    } else {
#pragma unroll 2
      for (int u = 24; u < 32; ++u) M0_PAIR(2 * u, u * 64);
#pragma unroll
      for (int g = 0; g < 4; ++g) {
        f32x4 y0v = *(const f32x4*)&y0s[g * 16 + g16];
#pragma unroll
        for (int r = 0; r < 4; ++r) { acc0[g][r] *= y0v[r]; acc1[g][r] *= y0v[r]; }
      }
#pragma unroll 2
      for (int p = 0; p < 16; ++p) M0_PAIR(112 + 2 * p, 5120 + p * 64);
    }
    // exchange: wid1 gives g0,g1 ; wid0 gives g2,g3
    __syncthreads();
    if (wid == 1) {
      float* p = scratch + l * 20;
      *(f32x4*)(p + 0) = acc0[0]; *(f32x4*)(p + 4) = acc1[0];
      *(f32x4*)(p + 8) = acc0[1]; *(f32x4*)(p + 12) = acc1[1];
    } else {
      float* p = scratch + 1280 + l * 20;
      *(f32x4*)(p + 0) = acc0[2]; *(f32x4*)(p + 4) = acc1[2];
      *(f32x4*)(p + 8) = acc0[3]; *(f32x4*)(p + 12) = acc1[3];
    }
    __syncthreads();
    const int gb = (wid == 0) ? 0 : 2;
    const float* p = (wid == 0) ? (scratch + l * 20) : (scratch + 1280 + l * 20);
    f32x4 t0 = *(const f32x4*)(p + 0), t1 = *(const f32x4*)(p + 4);
    f32x4 t2 = *(const f32x4*)(p + 8), t3_ = *(const f32x4*)(p + 12);
    i32x4 dd0 = *(const i32x4*)&dsts[(gb + 0) * 16 + g16];
    i32x4 dd1 = *(const i32x4*)&dsts[(gb + 1) * 16 + g16];
#pragma unroll
    for (int r = 0; r < 4; ++r) {
      float* base = agg + (long)dd0[r] * 80;
      atomicAdd(base + lr, acc0[gb + 0][r] + t0[r]);
      atomicAdd(base + 16 + lr, acc1[gb + 0][r] + t1[r]);
    }
#pragma unroll
    for (int r = 0; r < 4; ++r) {
      float* base = agg + (long)dd1[r] * 80;
      atomicAdd(base + lr, acc0[gb + 1][r] + t2[r]);
      atomicAdd(base + 16 + lr, acc1[gb + 1][r] + t3_[r]);
    }
  } else {
    // ---- m1 waves ----
    f32x4 mx[4], my[4], mz[4], t3[4];
#pragma unroll
    for (int g = 0; g < 4; ++g) {
      mx[g] = (f32x4){0, 0, 0, 0}; my[g] = (f32x4){0, 0, 0, 0};
      mz[g] = (f32x4){0, 0, 0, 0}; t3[g] = (f32x4){0, 0, 0, 0};
    }
    if (wid == 2) {
#pragma unroll 2
      for (int u = 0; u < 8; ++u) W2_TILE(u);
#pragma unroll 2
      for (int u = 0; u < 16; ++u) W3_TILE(u);
    } else {
#pragma unroll 2
      for (int u = 8; u < 16; ++u) W2_TILE(u);
#pragma unroll 2
      for (int u = 16; u < 32; ++u) W3_TILE(u);
    }
    // finalize: m = y0*m(w2) + y1*t3(w3)
#pragma unroll
    for (int g = 0; g < 4; ++g) {
      f32x4 y0v = *(const f32x4*)&y0s[g * 16 + g16];
      f32x4 yx = *(const f32x4*)&y1s[g * 16 + g16];
      f32x4 yy = *(const f32x4*)&y1s[64 + g * 16 + g16];
      f32x4 yz = *(const f32x4*)&y1s[128 + g * 16 + g16];
#pragma unroll
      for (int r = 0; r < 4; ++r) {
        mx[g][r] = mx[g][r] * y0v[r] + yx[r] * t3[g][r];
        my[g][r] = my[g][r] * y0v[r] + yy[r] * t3[g][r];
        mz[g][r] = mz[g][r] * y0v[r] + yz[r] * t3[g][r];
      }
    }
    // exchange: wid3 gives g0,g1 ; wid2 gives g2,g3
    __syncthreads();
    if (wid == 3) {
      float* p = scratch + 2560 + l * 28;
      *(f32x4*)(p + 0) = mx[0]; *(f32x4*)(p + 4) = my[0]; *(f32x4*)(p + 8) = mz[0];
      *(f32x4*)(p + 12) = mx[1]; *(f32x4*)(p + 16) = my[1]; *(f32x4*)(p + 20) = mz[1];
    } else {
      float* p = scratch + 4352 + l * 28;
      *(f32x4*)(p + 0) = mx[2]; *(f32x4*)(p + 4) = my[2]; *(f32x4*)(p + 8) = mz[2];
      *(f32x4*)(p + 12) = mx[3]; *(f32x4*)(p + 16) = my[3]; *(f32x4*)(p + 20) = mz[3];
    }
    __syncthreads();
    const int gb = (wid == 2) ? 0 : 2;
    const float* p = (wid == 2) ? (scratch + 2560 + l * 28) : (scratch + 4352 + l * 28);
    f32x4 u0 = *(const f32x4*)(p + 0), u1 = *(const f32x4*)(p + 4);
    f32x4 u2 = *(const f32x4*)(p + 8), u3 = *(const f32x4*)(p + 12);
    f32x4 u4 = *(const f32x4*)(p + 16), u5 = *(const f32x4*)(p + 20);
    i32x4 dd0 = *(const i32x4*)&dsts[(gb + 0) * 16 + g16];
    i32x4 dd1 = *(const i32x4*)&dsts[(gb + 1) * 16 + g16];
#pragma unroll
    for (int r = 0; r < 4; ++r) {
      float* base = agg + (long)dd0[r] * 80;
      atomicAdd(base + 32 + lr * 3 + 0, mx[gb + 0][r] + u0[r]);
      atomicAdd(base + 32 + lr * 3 + 1, my[gb + 0][r] + u1[r]);
      atomicAdd(base + 32 + lr * 3 + 2, mz[gb + 0][r] + u2[r]);
    }
#pragma unroll
    for (int r = 0; r < 4; ++r) {
      float* base = agg + (long)dd1[r] * 80;
      atomicAdd(base + 32 + lr * 3 + 0, mx[gb + 1][r] + u3[r]);
      atomicAdd(base + 32 + lr * 3 + 1, my[gb + 1][r] + u4[r]);
      atomicAdd(base + 32 + lr * 3 + 2, mz[gb + 1][r] + u5[r]);
    }
  }
  if (tid < 64) atomicAdd(cnt + dsts[tid], 1.0f);
#undef M0_PAIR
#undef W2_TILE
#undef W3_TILE
}

__global__ __launch_bounds__(256) void node_a(
    const float* __restrict__ h, const float* __restrict__ A0,
    const float* __restrict__ A1p, const float* __restrict__ agg,
    const float* __restrict__ cnt, float* __restrict__ outpre,
    float* __restrict__ stats) {
  __shared__ float redw[4][80];
  const int tid = threadIdx.x;
  const int wid = tid >> 6, l = tid & 63;
  const int n = blockIdx.x * 256 + tid;
  float x0[32], x1[48];
#pragma unroll
  for (int w = 0; w < 32; w++) x0[w] = 0.f;
#pragma unroll
  for (int c = 0; c < 48; c++) x1[c] = 0.f;
  if (n < NN) {
    const float* hr = h + (long)n * 80;
    const float* ar = agg + (long)n * 80;
    float inv = 1.f / fmaxf(cnt[n], 1.f);
#pragma unroll 1
    for (int u = 0; u < 32; u++) {
      float hu = hr[u];
#pragma unroll
      for (int w = 0; w < 32; w++) x0[w] += hu * A0[u * 32 + w];
    }
#pragma unroll
    for (int w = 0; w < 32; w++) x0[w] = x0[w] * INV_SQRT_M0 + ar[w] * inv;
#pragma unroll 1
    for (int u = 0; u < 16; u++) {
      float a = hr[32 + u * 3], b_ = hr[33 + u * 3], c_ = hr[34 + u * 3];
#pragma unroll
      for (int w = 0; w < 16; w++) {
        float Aw = A1p[u * 16 + w];
        x1[w * 3 + 0] += a * Aw;
        x1[w * 3 + 1] += b_ * Aw;
        x1[w * 3 + 2] += c_ * Aw;
      }
    }
#pragma unroll
    for (int c = 0; c < 48; c++) x1[c] = x1[c] * INV_SQRT_M1 + ar[32 + c] * inv;
    float* opr = outpre + (long)n * 80;
#pragma unroll
    for (int w = 0; w < 32; w++) opr[w] = x0[w];
#pragma unroll
    for (int c = 0; c < 48; c++) opr[32 + c] = x1[c];
  }
#pragma unroll 1
  for (int c = 0; c < 32; ++c) {
    float s = x0[c];
#pragma unroll
    for (int m = 32; m >= 1; m >>= 1) s += __shfl_xor(s, m, 64);
    if (l == 0) redw[wid][c] = s;
  }
#pragma unroll 1
  for (int c = 0; c < 32; ++c) {
    float v = x0[c];
    float s = v * v;
#pragma unroll
    for (int m = 32; m >= 1; m >>= 1) s += __shfl_xor(s, m, 64);
    if (l == 0) redw[wid][32 + c] = s;
  }
#pragma unroll 1
  for (int u = 0; u < 16; ++u) {
    float s = x1[u * 3] * x1[u * 3] + x1[u * 3 + 1] * x1[u * 3 + 1] +
              x1[u * 3 + 2] * x1[u * 3 + 2];
#pragma unroll
    for (int m = 32; m >= 1; m >>= 1) s += __shfl_xor(s, m, 64);
    if (l == 0) redw[wid][64 + u] = s;
  }
  __syncthreads();
  if (tid < 80)
    atomicAdd(&stats[tid],
              redw[0][tid] + redw[1][tid] + redw[2][tid] + redw[3][tid]);
}

__global__ void node_b(const float* __restrict__ outpre, const float* __restrict__ stats,
                       const float* __restrict__ bnw0, const float* __restrict__ bnb0,
                       const float* __restrict__ bnw1, const float* __restrict__ h,
                       float* __restrict__ out) {
  int idx = blockIdx.x * 256 + threadIdx.x;
  if (idx >= NN * 80) return;
  int c = idx % 80;
  float v = outpre[idx];
  const float invN = 1.f / NN;
  float o;
  if (c < 32) {
    float mu = stats[c] * invN;
    float var = stats[32 + c] * invN - mu * mu;
    o = (v - mu) * rsqrtf(var + EPSV) * bnw0[c] + bnb0[c];
  } else {
    int u = (c - 32) / 3;
    float nr = stats[64 + u] * invN;
    o = v * rsqrtf(nr + EPSV) * bnw1[u];
  }
  out[idx] = o + h[idx];
}

extern "C" void kernel_launch(void* const* d_in, const int* in_sizes, int n_in,
                              void* d_out, int out_size, void* d_ws, size_t ws_size,
                              hipStream_t stream) {
  const float* h    = (const float*)d_in[0];
  const int*   eidx = (const int*)d_in[1];
  const float* esh  = (const float*)d_in[2];
  const float* ef   = (const float*)d_in[3];
  const float* W1   = (const float*)d_in[4];
  const float* b1   = (const float*)d_in[5];
  const float* W2   = (const float*)d_in[6];
  const float* b2   = (const float*)d_in[7];
  const float* W3   = (const float*)d_in[8];
  const float* b3   = (const float*)d_in[9];
  const float* A0   = (const float*)d_in[10];
  const float* A1p  = (const float*)d_in[11];
  const float* bnw0 = (const float*)d_in[12];
  const float* bnb0 = (const float*)d_in[13];
  const float* bnw1 = (const float*)d_in[14];
  float* out = (float*)d_out;

  float* ws = (float*)d_ws;
  float* agg    = ws;             // 800000
  float* cnt    = ws + 800000;    // 10000
  float* stats  = ws + 810000;    // 80
  float* outpre = ws + 810080;    // 800000
  short* W3P    = (short*)(ws + 1610080);  // 147456 shorts
  short* W1P    = W3P + WNUM * 64;         // 4096 shorts
  short* W2P    = W1P + 4096;              // 4096 shorts

  hipMemsetAsync(agg, 0, (size_t)810080 * sizeof(float), stream);

  prep_weights<<<(WNUM * 64 + 8192 + 255) / 256, 256, 0, stream>>>(W1, W2, W3, W1P,
                                                                   W2P, W3P);
  edge_kernel<<<NE / 64, 256, 0, stream>>>(h, eidx, esh, ef, W1P, b1, W2P, b2, W3P, b3,
                                           agg, cnt);
  node_a<<<(NN + 255) / 256, 256, 0, stream>>>(h, A0, A1p, agg, cnt, outpre, stats);
  node_b<<<(NN * 80 + 255) / 256, 256, 0, stream>>>(outpre, stats, bnw0, bnb0, bnw1, h,
                                                    out);
}